// Round 9
// baseline (229.967 us; speedup 1.0000x reference)
//
#include <hip/hip_runtime.h>

#define D_MODEL 1024
#define N_HEADS 16
#define HEAD_DIM 64
#define SEQ 2048
#define BATCH 2
#define M_TOTAL (BATCH*SEQ)   // 4096

typedef __bf16 bf16;
typedef __bf16 bf16x8 __attribute__((ext_vector_type(8)));
typedef __bf16 bf16x4 __attribute__((ext_vector_type(4)));
typedef float  floatx4 __attribute__((ext_vector_type(4)));
typedef short  shortx4 __attribute__((ext_vector_type(4)));

#if __has_builtin(__builtin_amdgcn_exp2f)
#define EXP2F(x) __builtin_amdgcn_exp2f(x)
#else
#define EXP2F(x) __expf(0.69314718f * (x))
#endif

// 16x16x16 bf16 MFMA: B-operand layout (n=lane&15, k=quad*4+j) exactly matches
// the 16x16x32 D-layout (col=lane&15, row=quad*4+r) -> P feeds PV directly from
// registers, no LDS round trip, no cross-lane movement.
__device__ __forceinline__ floatx4 mfma16(bf16x4 a, bf16x4 b, floatx4 c) {
#if __has_builtin(__builtin_amdgcn_mfma_f32_16x16x16_bf16)
    return __builtin_amdgcn_mfma_f32_16x16x16_bf16(a, b, c, 0, 0, 0);
#else
    return __builtin_amdgcn_mfma_f32_16x16x16bf16_1k(
        __builtin_bit_cast(shortx4, a), __builtin_bit_cast(shortx4, b), c, 0, 0, 0);
#endif
}

// async global->LDS, 16B per lane (flash only).
__device__ __forceinline__ void gl2lds16(const bf16* g, bf16* l) {
    __builtin_amdgcn_global_load_lds(
        (const __attribute__((address_space(1))) unsigned int*)g,
        (__attribute__((address_space(3))) unsigned int*)l, 16, 0, 0);
}

// counted-vmcnt barrier (flash only).
#define WAITBAR(N) asm volatile("s_waitcnt vmcnt(" #N ")\n\ts_barrier" ::: "memory")

// ---------------------------------------------------------------------------
// one combined fp32->bf16 conversion for q (1M float4), Wq (256K), Wo (256K)
// ---------------------------------------------------------------------------
__global__ void cvt_all(const float* __restrict__ q, const float* __restrict__ Wq,
                        const float* __restrict__ Wo, bf16* __restrict__ qb,
                        bf16* __restrict__ wqb, bf16* __restrict__ wob) {
    int i = blockIdx.x * 256 + threadIdx.x;       // 0 .. 1572863
    const float* src; bf16* dst; int off;
    if (i < 1048576)      { src = q;  dst = qb;  off = i; }
    else if (i < 1310720) { src = Wq; dst = wqb; off = i - 1048576; }
    else                  { src = Wo; dst = wob; off = i - 1310720; }
    float4 v = ((const float4*)src)[off];
    bf16x4 o;
    o[0] = (bf16)v.x; o[1] = (bf16)v.y; o[2] = (bf16)v.z; o[3] = (bf16)v.w;
    ((bf16x4*)dst)[off] = o;
}

// ---------------------------------------------------------------------------
// GEMM C = A * B^T + bias, round 9: BARRIER-FREE, LDS-FREE K-loop.
// Rationale: 8 rounds of staged variants all plateaued ~44us; m233 ablation
// says stage+vmcnt+barrier is ~72% of a 2-phase GEMM; A (1MB/XCD after pin)
// and B (2MB) are L2-resident with 16-32x reuse -> don't stage what L2 fits.
// Fragments load DIRECTLY from global: per-lane base pointers are
// loop-invariant, K-offsets fold into 13-bit immediates (max 1984B < 4095).
// Register double-buffer X/Y, distance-1 prefetch (12 b128 loads for t+1
// issued before 16 MFMA on t), fully static unroll (rule #20).
// Tile 128(M)x64(N), wave = 64x32 quadrant (acc 4x2), grid 512, XCD-pinned.
// A-line use: per af[i] the wave's 4 quads read 16 rows x 64B; ks=0/1 cover
// the full 128B line -> lines fully consumed within one K-step. Waves 0/1
// share A rows, waves 0/2 share B rows -> L1 temporal reuse.
// LDS: 16KB, used ONLY by MODE1's epilogue transpose.
// Frag layouts (HW-verified): A m=lane&15,k=quad*8+j; C/D col=lane&15,row=quad*4+r.
// MODE 0: fp32 out row-major + bias.
// MODE 1: bf16 out to projbf [B,H,S,Dh] + projT [B,H,Dh,S] via in-LDS transpose.
// ---------------------------------------------------------------------------
template<int MODE>
__global__ __launch_bounds__(256, 2)
void gemm_bt_bias_t(const bf16* __restrict__ A, const bf16* __restrict__ B,
                    const float* __restrict__ bias, void* __restrict__ Cout,
                    bf16* __restrict__ Cout2, int M, int N, int K)
{
    __shared__ __align__(16) bf16 smem[8192];   // MODE1 transpose only (16KB)

    const int tid  = threadIdx.x;
    const int lane = tid & 63;
    const int wave = tid >> 6;             // 0..3
    const int quad = lane >> 4;
    const int l16  = lane & 15;
    const int lin  = blockIdx.x;           // 0..511
    const int m0   = ((lin & 7) * 4 + ((lin >> 3) & 3)) * 128;  // XCD-pinned m-strip
    const int n0   = (lin >> 5) * 64;
    const int wm   = (wave >> 1) * 64;
    const int wn   = (wave & 1) * 32;

    floatx4 acc[4][2];
#pragma unroll
    for (int i = 0; i < 4; i++)
#pragma unroll
        for (int j = 0; j < 2; j++) acc[i][j] = (floatx4){0.f, 0.f, 0.f, 0.f};

    // loop-invariant per-lane fragment base pointers (K offsets become imms)
    const bf16* pA[4];
    const bf16* pB[2];
#pragma unroll
    for (int i = 0; i < 4; i++)
        pA[i] = A + (size_t)(m0 + wm + i * 16 + l16) * K + quad * 8;
#pragma unroll
    for (int j = 0; j < 2; j++)
        pB[j] = B + (size_t)(n0 + wn + j * 16 + l16) * K + quad * 8;

    // one K-step = 64 elems (2 MFMA sub-steps of 32); frag set = 8 af + 4 bf
    bf16x8 afX[4][2], bfX[2][2], afY[4][2], bfY[2][2];

#define LDSET(af_, bf_, kk)                                                  \
    {                                                                        \
        _Pragma("unroll")                                                    \
        for (int i = 0; i < 4; i++) {                                        \
            _Pragma("unroll")                                                \
            for (int ks = 0; ks < 2; ks++)                                   \
                af_[i][ks] = *(const bf16x8*)(pA[i] + (kk) + ks * 32);       \
        }                                                                    \
        _Pragma("unroll")                                                    \
        for (int j = 0; j < 2; j++) {                                        \
            _Pragma("unroll")                                                \
            for (int ks = 0; ks < 2; ks++)                                   \
                bf_[j][ks] = *(const bf16x8*)(pB[j] + (kk) + ks * 32);       \
        }                                                                    \
    }

#define MFMASET(af_, bf_)                                                    \
    {                                                                        \
        _Pragma("unroll")                                                    \
        for (int ks = 0; ks < 2; ks++) {                                     \
            _Pragma("unroll")                                                \
            for (int i = 0; i < 4; i++) {                                    \
                _Pragma("unroll")                                            \
                for (int j = 0; j < 2; j++)                                  \
                    acc[i][j] = __builtin_amdgcn_mfma_f32_16x16x32_bf16(     \
                        af_[i][ks], bf_[j][ks], acc[i][j], 0, 0, 0);         \
            }                                                                \
        }                                                                    \
    }

    // NT = 16 K-steps (K=1024), X/Y rotate, distance-1 prefetch, no barriers.
    LDSET(afX, bfX, 0);
#pragma unroll
    for (int tt = 0; tt < 8; tt++) {
        const int t0 = tt * 2;
        if (t0 + 1 < 16) LDSET(afY, bfY, (t0 + 1) * 64);
        MFMASET(afX, bfX);
        if (t0 + 2 < 16) LDSET(afX, bfX, (t0 + 2) * 64);
        MFMASET(afY, bfY);
    }
#undef LDSET
#undef MFMASET

    if constexpr (MODE == 0) {
        float* C = (float*)Cout;
#pragma unroll
        for (int j = 0; j < 2; j++) {
            int col  = n0 + wn + j * 16 + l16;
            float bv = bias[col];
#pragma unroll
            for (int i = 0; i < 4; i++) {
                int rbase = m0 + wm + i * 16 + quad * 4;
#pragma unroll
                for (int r = 0; r < 4; r++)
                    C[(size_t)(rbase + r) * N + col] = acc[i][j][r] + bv;
            }
        }
    } else {
        bf16* Cb = (bf16*)Cout;
        const int h  = n0 >> 6;          // tile spans exactly one head
        const int b  = m0 >> 11;         // tile never crosses batch boundary
        bf16x4 tile[4][2];
#pragma unroll
        for (int j = 0; j < 2; j++) {
            int dL   = wn + j * 16 + l16;            // 0..63
            float bv = bias[n0 + dL];
#pragma unroll
            for (int i = 0; i < 4; i++) {
                int sl = wm + i * 16 + quad * 4;     // local s, 0..127
                int s0 = (m0 & 2047) + sl;
#pragma unroll
                for (int r = 0; r < 4; r++) {
                    float v = acc[i][j][r] + bv;
                    tile[i][j][r] = (bf16)v;
                    Cb[(((size_t)(b * N_HEADS + h) * SEQ + (s0 + r)) << 6) + dL] = (bf16)v;
                }
            }
        }
        // in-LDS transpose: T[dL=64][sL=128] (16KB), chunk swizzle
        // phys = (sl>>3) ^ (dL&15)
        __syncthreads();
#pragma unroll
        for (int j = 0; j < 2; j++) {
            int dL = wn + j * 16 + l16;
#pragma unroll
            for (int i = 0; i < 4; i++) {
                int sl = wm + i * 16 + quad * 4;
                *(bf16x4*)&smem[dL * 128 + (((sl >> 3) ^ (dL & 15)) * 8) + (sl & 7)] =
                    tile[i][j];
            }
        }
        __syncthreads();
        // coalesced projT stores: thread -> (dL = tid>>2, 4 chunks of 16B)
        {
            int dL    = tid >> 2;
            int sbase = m0 & 2047;
            bf16* dstrow = Cout2 + ((size_t)(b * N_HEADS + h) * 64 + dL) * SEQ + sbase;
#pragma unroll
            for (int cc = 0; cc < 4; cc++) {
                int c    = (tid & 3) * 4 + cc;
                int phys = c ^ (dL & 15);
                *(bf16x8*)(dstrow + c * 8) = *(const bf16x8*)&smem[dL * 128 + phys * 8];
            }
        }
    }
}

// ---------------------------------------------------------------------------
// MFMA flash attention — r5 kernel VERBATIM, single 512-block dispatch
// (57.5us proven; r8 showed 2x256-block split at 1 blk/CU costs ~+30us total:
// flash needs >=2 blk/CU for cross-block overlap of its barrier drains).
// ---------------------------------------------------------------------------
__global__ __launch_bounds__(256, 3)
void flash_attn(const bf16* __restrict__ projbf, const bf16* __restrict__ projT,
                bf16* __restrict__ vals)
{
    __shared__ __align__(16) bf16 Ks[3][64 * 64];   // 3 x 8 KB
    __shared__ __align__(16) bf16 Vt[3][64 * 64];   // 3 x 8 KB -> 48KB total

    const int tid  = threadIdx.x;
    const int lane = tid & 63;
    const int wave = tid >> 6;          // 0..3
    const int quad = lane >> 4;
    const int l16  = lane & 15;
    const int lin  = blockIdx.x;        // 0..511
    const int bh   = (lin & 7) * 4 + (lin >> 7);     // XCD-pinned head
    const int q0   = ((lin >> 3) & 15) * 128;        // q-tile of 128
    const bf16* hK  = projbf + (size_t)bh * SEQ * 64;
    const bf16* hVt = projT  + (size_t)bh * 64 * SEQ;
    const int wq0  = wave * 32;

    // persistent Q B-frags: qf[nb][ks], n=q (16 per nb), k=d
    // prescaled by 1/(8*ln2) so exp2(S') needs no per-score fma.
    bf16x8 qf[2][2];
#pragma unroll
    for (int nbi = 0; nbi < 2; nbi++)
#pragma unroll
        for (int ks = 0; ks < 2; ks++) {
            bf16x8 v = *(const bf16x8*)(hK + (size_t)(q0 + wq0 + nbi * 16 + l16) * 64
                                        + ks * 32 + quad * 8);
#pragma unroll
            for (int e = 0; e < 8; e++)
                v[e] = (bf16)((float)v[e] * 0.18033688f);
            qf[nbi][ks] = v;
        }
    // drain Q loads so in-loop vmcnt counts only DMA
    asm volatile("s_waitcnt vmcnt(0)" ::: "memory");

    bf16x4 ones;
#pragma unroll
    for (int e = 0; e < 4; e++) ones[e] = (bf16)1.0f;

    floatx4 oacc[4][2];                 // [mb=d-block][nb=q-block]
#pragma unroll
    for (int mb = 0; mb < 4; mb++)
#pragma unroll
        for (int nbi = 0; nbi < 2; nbi++) oacc[mb][nbi] = (floatx4){0.f, 0.f, 0.f, 0.f};
    floatx4 lacc[2];                    // ones-MFMA row-sum accumulators
#pragma unroll
    for (int nbi = 0; nbi < 2; nbi++) lacc[nbi] = (floatx4){0.f, 0.f, 0.f, 0.f};

    // DMA one 64-key K+V tile pair (16 KB): 2+2 = 4 vmem/thread
    auto issue = [&](int buf, int k0) {
#pragma unroll
        for (int it = 0; it < 2; it++) {
            int s = it * 256 + tid;          // 0..511 chunk slots
            int row = s >> 3, cl = (s & 7) ^ (row & 7);
            gl2lds16(hK + (size_t)(k0 + row) * 64 + cl * 8, &Ks[buf][s * 8]);
        }
#pragma unroll
        for (int it = 0; it < 2; it++) {
            int s = it * 256 + tid;
            int row = s >> 3, cl = (s & 7) ^ (row & 7);
            gl2lds16(hVt + (size_t)row * SEQ + k0 + cl * 8, &Vt[buf][s * 8]);
        }
    };

    auto compute = [&](int buf) {
#pragma unroll
        for (int kc = 0; kc < 4; kc++) {            // 16-key chunks
            // ---- S'^T: D[key=kc*16+quad*4+r][q=l16] per nb ----
            int krow = kc * 16 + l16;
            bf16x8 kf0 = *(const bf16x8*)&Ks[buf][krow * 64 + ((quad ^ (krow & 7)) * 8)];
            bf16x8 kf1 = *(const bf16x8*)&Ks[buf][krow * 64 + (((4 + quad) ^ (krow & 7)) * 8)];
            bf16x4 p4[2];
#pragma unroll
            for (int nbi = 0; nbi < 2; nbi++) {
                floatx4 s = __builtin_amdgcn_mfma_f32_16x16x32_bf16(
                    kf0, qf[nbi][0], (floatx4){0.f, 0.f, 0.f, 0.f}, 0, 0, 0);
                s = __builtin_amdgcn_mfma_f32_16x16x32_bf16(
                    kf1, qf[nbi][1], s, 0, 0, 0);
#pragma unroll
                for (int r = 0; r < 4; r++)
                    p4[nbi][r] = (bf16)EXP2F(s[r]);
            }
            // ---- PV + row-sum over these 16 keys ----
#pragma unroll
            for (int nbi = 0; nbi < 2; nbi++)
                lacc[nbi] = mfma16(ones, p4[nbi], lacc[nbi]);
#pragma unroll
            for (int mb = 0; mb < 4; mb++) {
                int vrow = mb * 16 + l16;
                int c    = kc * 2 + (quad >> 1);     // 16B chunk holding keys quad*4..+3
                bf16x4 vf = *(const bf16x4*)&Vt[buf][vrow * 64
                                + ((c ^ (vrow & 7)) * 8) + (quad & 1) * 4];
#pragma unroll
                for (int nbi = 0; nbi < 2; nbi++)
                    oacc[mb][nbi] = mfma16(vf, p4[nbi], oacc[mb][nbi]);
            }
        }
    };

    issue(0, 0);
    issue(1, 64);
    for (int t = 0; t < 31; ++t) {
        WAITBAR(4);                      // tile t landed; t+1's 4 still in flight
        if (t < 30) issue((t + 2) % 3, (t + 2) * 64);
        compute(t % 3);
    }
    WAITBAR(0);                          // tile 31: full drain
    compute(1);                          // 31 % 3

    // lacc[nbi][*]: all 4 values = sum over all keys for col q=l16 (A=ones
    // makes D rows identical) -> per-lane reciprocal, no shuffles.
    const int b = bh >> 4, h = bh & 15;
#pragma unroll
    for (int nbi = 0; nbi < 2; nbi++) {
        float rinv = 1.0f / lacc[nbi][0];
        int q = q0 + wq0 + nbi * 16 + l16;
#pragma unroll
        for (int mb = 0; mb < 4; mb++) {
            bf16x4 o4;
#pragma unroll
            for (int r = 0; r < 4; r++) o4[r] = (bf16)(oacc[mb][nbi][r] * rinv);
            *(bf16x4*)&vals[((size_t)b * SEQ + q) * D_MODEL + h * 64 + mb * 16 + quad * 4] = o4;
        }
    }
}

// ---------------------------------------------------------------------------
extern "C" void kernel_launch(void* const* d_in, const int* in_sizes, int n_in,
                              void* d_out, int out_size, void* d_ws, size_t ws_size,
                              hipStream_t stream)
{
    const float* q  = (const float*)d_in[0];
    const float* Wq = (const float*)d_in[1];
    const float* bq = (const float*)d_in[2];
    const float* Wo = (const float*)d_in[3];
    const float* bo = (const float*)d_in[4];
    float* out = (float*)d_out;

    char* ws = (char*)d_ws;
    bf16* qbf    = (bf16*)(ws);                        // 8 MB
    bf16* Wqbf   = (bf16*)(ws + (size_t)( 8 << 20));   // 2 MB
    bf16* Wobf   = (bf16*)(ws + (size_t)(10 << 20));   // 2 MB
    bf16* projbf = (bf16*)(ws + (size_t)(12 << 20));   // 8 MB  [B,H,S,Dh]
    bf16* projT  = (bf16*)(ws + (size_t)(20 << 20));   // 8 MB  [B,H,Dh,S]
    bf16* valsb  = (bf16*)(ws + (size_t)(28 << 20));   // 8 MB  [B,S,D]

    cvt_all<<<6144, 256, 0, stream>>>(q, Wq, Wo, qbf, Wqbf, Wobf);

    // proj = q @ Wq^T + bq -> projbf [B,H,S,Dh] + projT [B,H,Dh,S]
    gemm_bt_bias_t<1><<<512, 256, 0, stream>>>(qbf, Wqbf, bq, (void*)projbf,
                                               projT, M_TOTAL, D_MODEL, D_MODEL);

    flash_attn<<<512, 256, 0, stream>>>(projbf, projT, valsb);

    gemm_bt_bias_t<0><<<512, 256, 0, stream>>>(valsb, Wobf, bo, (void*)out,
                                               nullptr, M_TOTAL, D_MODEL, D_MODEL);
}

// Round 10
// 160.465 us; speedup vs baseline: 1.4331x; 1.4331x over previous
//
#include <hip/hip_runtime.h>

#define D_MODEL 1024
#define N_HEADS 16
#define HEAD_DIM 64
#define SEQ 2048
#define BATCH 2
#define M_TOTAL (BATCH*SEQ)   // 4096

typedef __bf16 bf16;
typedef __bf16 bf16x8 __attribute__((ext_vector_type(8)));
typedef __bf16 bf16x4 __attribute__((ext_vector_type(4)));
typedef float  floatx4 __attribute__((ext_vector_type(4)));
typedef short  shortx4 __attribute__((ext_vector_type(4)));

#if __has_builtin(__builtin_amdgcn_exp2f)
#define EXP2F(x) __builtin_amdgcn_exp2f(x)
#else
#define EXP2F(x) __expf(0.69314718f * (x))
#endif

// 16x16x16 bf16 MFMA: B-operand layout (n=lane&15, k=quad*4+j) exactly matches
// the 16x16x32 D-layout (col=lane&15, row=quad*4+r) -> P feeds PV directly from
// registers, no LDS round trip, no cross-lane movement.
__device__ __forceinline__ floatx4 mfma16(bf16x4 a, bf16x4 b, floatx4 c) {
#if __has_builtin(__builtin_amdgcn_mfma_f32_16x16x16_bf16)
    return __builtin_amdgcn_mfma_f32_16x16x16_bf16(a, b, c, 0, 0, 0);
#else
    return __builtin_amdgcn_mfma_f32_16x16x16bf16_1k(
        __builtin_bit_cast(shortx4, a), __builtin_bit_cast(shortx4, b), c, 0, 0, 0);
#endif
}

// async global->LDS, 16B per lane. LDS dest is wave-uniform base + lane*16;
// conflicts handled by XOR-swizzle of 16B chunks applied to the GLOBAL source
// address (free).
__device__ __forceinline__ void gl2lds16(const bf16* g, bf16* l) {
    __builtin_amdgcn_global_load_lds(
        (const __attribute__((address_space(1))) unsigned int*)g,
        (__attribute__((address_space(3))) unsigned int*)l, 16, 0, 0);
}

// counted-vmcnt barrier: wait until at most N vmem ops outstanding, then
// s_barrier — WITHOUT the full vmcnt(0) drain __syncthreads() forces.
#define WAITBAR(N) asm volatile("s_waitcnt vmcnt(" #N ")\n\ts_barrier" ::: "memory")

// ---------------------------------------------------------------------------
// one combined fp32->bf16 conversion for q (1M float4), Wq (256K), Wo (256K)
// (standalone cvt beats in-staging fusion: r7 showed per-block duplicated
// B-conversion costs more than the 36MB pass here.)
// ---------------------------------------------------------------------------
__global__ void cvt_all(const float* __restrict__ q, const float* __restrict__ Wq,
                        const float* __restrict__ Wo, bf16* __restrict__ qb,
                        bf16* __restrict__ wqb, bf16* __restrict__ wob) {
    int i = blockIdx.x * 256 + threadIdx.x;       // 0 .. 1572863
    const float* src; bf16* dst; int off;
    if (i < 1048576)      { src = q;  dst = qb;  off = i; }
    else if (i < 1310720) { src = Wq; dst = wqb; off = i - 1048576; }
    else                  { src = Wo; dst = wob; off = i - 1310720; }
    float4 v = ((const float4*)src)[off];
    bf16x4 o;
    o[0] = (bf16)v.x; o[1] = (bf16)v.y; o[2] = (bf16)v.z; o[3] = (bf16)v.w;
    ((bf16x4*)dst)[off] = o;
}

// ---------------------------------------------------------------------------
// GEMM C = A * B^T + bias — r3 version VERBATIM (empirical optimum across 7
// structural variants r0-r9: barrier type, BK, tile shape, occupancy, staging
// mode, direct-L2 all plateau >= this at ~44us; direct-L2 r9 was 2x WORSE ->
// DMA staging through LDS is load-bearing).
// 128(M)x64(N) tile, BK=64, 16 K-steps, 3-buffer / 2-deep DMA prefetch,
// counted vmcnt(6)+s_barrier per step. LDS 72KB -> 2 blocks/CU. Grid 512,
// XCD-pinned. Tiles unpadded [row][64], chunk swizzle phys=c^(row&7).
// Frag layouts (HW-verified): A m=lane&15,k=quad*8+j; C/D col=lane&15,row=quad*4+r.
// MODE 0: fp32 out row-major + bias.
// MODE 1: bf16 out to projbf [B,H,S,Dh] + projT [B,H,Dh,S] via in-LDS transpose.
// ---------------------------------------------------------------------------
template<int MODE>
__global__ __launch_bounds__(256, 2)
void gemm_bt_bias_t(const bf16* __restrict__ A, const bf16* __restrict__ B,
                    const float* __restrict__ bias, void* __restrict__ Cout,
                    bf16* __restrict__ Cout2, int M, int N, int K)
{
    // 3 bufs x (As 8192 + Bs 4096 elems) = 36864 elems = 72KB
    __shared__ __align__(16) bf16 smem[36864];

    const int tid  = threadIdx.x;
    const int lane = tid & 63;
    const int wave = tid >> 6;             // 0..3
    const int quad = lane >> 4;
    const int l16  = lane & 15;
    const int lin  = blockIdx.x;           // 0..511
    const int m0   = ((lin & 7) * 4 + ((lin >> 3) & 3)) * 128;  // XCD-pinned m-strip
    const int n0   = (lin >> 5) * 64;
    const int wm   = (wave >> 1) * 64;
    const int wn   = (wave & 1) * 32;

    floatx4 acc[4][2];
#pragma unroll
    for (int i = 0; i < 4; i++)
#pragma unroll
        for (int j = 0; j < 2; j++) acc[i][j] = (floatx4){0.f, 0.f, 0.f, 0.f};

    // stage one 24KB tile pair into buf at elem-offset `base`:
    // A 16KB (4 issues/thread), B 8KB (2 issues) = 6 vmem/thread
    auto issue = [&](int base, int k0) {
#pragma unroll
        for (int it = 0; it < 4; it++) {
            int s = it * 256 + tid;          // 0..1023 chunk slots
            int row = s >> 3, cl = (s & 7) ^ (row & 7);
            gl2lds16(A + (size_t)(m0 + row) * K + k0 + cl * 8, &smem[base + s * 8]);
        }
#pragma unroll
        for (int it = 0; it < 2; it++) {
            int s = it * 256 + tid;          // 0..511
            int row = s >> 3, cl = (s & 7) ^ (row & 7);
            gl2lds16(B + (size_t)(n0 + row) * K + k0 + cl * 8, &smem[base + 8192 + s * 8]);
        }
    };

    auto compute = [&](int base) {
#pragma unroll
        for (int ks = 0; ks < 2; ks++) {
            bf16x8 af[4], bfr[2];
#pragma unroll
            for (int i = 0; i < 4; i++) {
                int row = wm + i * 16 + l16;
                int phys = (ks * 4 + quad) ^ (row & 7);
                af[i] = *(const bf16x8*)&smem[base + row * 64 + phys * 8];
            }
#pragma unroll
            for (int j = 0; j < 2; j++) {
                int row = wn + j * 16 + l16;
                int phys = (ks * 4 + quad) ^ (row & 7);
                bfr[j] = *(const bf16x8*)&smem[base + 8192 + row * 64 + phys * 8];
            }
#pragma unroll
            for (int i = 0; i < 4; i++)
#pragma unroll
                for (int j = 0; j < 2; j++)
                    acc[i][j] = __builtin_amdgcn_mfma_f32_16x16x32_bf16(
                        af[i], bfr[j], acc[i][j], 0, 0, 0);
        }
    };

    const int NT = K >> 6;                  // 16
    issue(0, 0);
    issue(12288, 64);
    for (int t = 0; t < NT - 1; ++t) {
        WAITBAR(6);                         // tile t landed; t+1's 6 still in flight
        if (t + 2 < NT) issue(((t + 2) % 3) * 12288, (t + 2) << 6);
        compute((t % 3) * 12288);
    }
    WAITBAR(0);                             // last tile: full drain
    compute(((NT - 1) % 3) * 12288);

    if constexpr (MODE == 0) {
        float* C = (float*)Cout;
#pragma unroll
        for (int j = 0; j < 2; j++) {
            int col  = n0 + wn + j * 16 + l16;
            float bv = bias[col];
#pragma unroll
            for (int i = 0; i < 4; i++) {
                int rbase = m0 + wm + i * 16 + quad * 4;
#pragma unroll
                for (int r = 0; r < 4; r++)
                    C[(size_t)(rbase + r) * N + col] = acc[i][j][r] + bv;
            }
        }
    } else {
        bf16* Cb = (bf16*)Cout;
        const int h  = n0 >> 6;          // tile spans exactly one head
        const int b  = m0 >> 11;         // tile never crosses batch boundary
        bf16x4 tile[4][2];
#pragma unroll
        for (int j = 0; j < 2; j++) {
            int dL   = wn + j * 16 + l16;            // 0..63
            float bv = bias[n0 + dL];
#pragma unroll
            for (int i = 0; i < 4; i++) {
                int sl = wm + i * 16 + quad * 4;     // local s, 0..127
                int s0 = (m0 & 2047) + sl;
#pragma unroll
                for (int r = 0; r < 4; r++) {
                    float v = acc[i][j][r] + bv;
                    tile[i][j][r] = (bf16)v;
                    Cb[(((size_t)(b * N_HEADS + h) * SEQ + (s0 + r)) << 6) + dL] = (bf16)v;
                }
            }
        }
        // in-LDS transpose: T[dL=64][sL=128] (16KB, reuse smem),
        // 16B-chunk swizzle phys = (sl>>3) ^ (dL&15)
        __syncthreads();
#pragma unroll
        for (int j = 0; j < 2; j++) {
            int dL = wn + j * 16 + l16;
#pragma unroll
            for (int i = 0; i < 4; i++) {
                int sl = wm + i * 16 + quad * 4;
                *(bf16x4*)&smem[dL * 128 + (((sl >> 3) ^ (dL & 15)) * 8) + (sl & 7)] =
                    tile[i][j];
            }
        }
        __syncthreads();
        // coalesced projT stores: thread -> (dL = tid>>2, 4 chunks of 16B)
        {
            int dL    = tid >> 2;
            int sbase = m0 & 2047;
            bf16* dstrow = Cout2 + ((size_t)(b * N_HEADS + h) * 64 + dL) * SEQ + sbase;
#pragma unroll
            for (int cc = 0; cc < 4; cc++) {
                int c    = (tid & 3) * 4 + cc;
                int phys = c ^ (dL & 15);
                *(bf16x8*)(dstrow + c * 8) = *(const bf16x8*)&smem[dL * 128 + phys * 8];
            }
        }
    }
}

// ---------------------------------------------------------------------------
// MFMA flash attention — converged kernel (57.5/57.7/58.4us across 3 runs).
// Structure: 3-buf/2-deep DMA prefetch, WAITBAR(4) per 64-key tile, 128
// q/block, nb=2, register-P 16x16x16 PV, grid 512 (2 blocks/CU), XCD-pinned.
// Q prescaled by 1/(8 ln2); p = exp2(S') (stabilizer cancels in O/sum(p));
// row-sums via ones-MFMA. No setprio (r4: hurts lockstep). TLP null (r1/r2),
// VALU null (r4), LDS traffic null (r2) — remaining limiter is the intra-wave
// S->exp->PV chain (T16-class rewrite territory).
// ---------------------------------------------------------------------------
__global__ __launch_bounds__(256, 3)
void flash_attn(const bf16* __restrict__ projbf, const bf16* __restrict__ projT,
                bf16* __restrict__ vals)
{
    __shared__ __align__(16) bf16 Ks[3][64 * 64];   // 3 x 8 KB
    __shared__ __align__(16) bf16 Vt[3][64 * 64];   // 3 x 8 KB -> 48KB total

    const int tid  = threadIdx.x;
    const int lane = tid & 63;
    const int wave = tid >> 6;          // 0..3
    const int quad = lane >> 4;
    const int l16  = lane & 15;
    const int lin  = blockIdx.x;        // 0..511
    const int bh   = (lin & 7) * 4 + (lin >> 7);     // XCD-pinned head
    const int q0   = ((lin >> 3) & 15) * 128;        // q-tile of 128
    const bf16* hK  = projbf + (size_t)bh * SEQ * 64;
    const bf16* hVt = projT  + (size_t)bh * 64 * SEQ;
    const int wq0  = wave * 32;

    // persistent Q B-frags: qf[nb][ks], n=q (16 per nb), k=d
    // prescaled by 1/(8*ln2) so exp2(S') needs no per-score fma.
    bf16x8 qf[2][2];
#pragma unroll
    for (int nbi = 0; nbi < 2; nbi++)
#pragma unroll
        for (int ks = 0; ks < 2; ks++) {
            bf16x8 v = *(const bf16x8*)(hK + (size_t)(q0 + wq0 + nbi * 16 + l16) * 64
                                        + ks * 32 + quad * 8);
#pragma unroll
            for (int e = 0; e < 8; e++)
                v[e] = (bf16)((float)v[e] * 0.18033688f);
            qf[nbi][ks] = v;
        }
    // drain Q loads so in-loop vmcnt counts only DMA
    asm volatile("s_waitcnt vmcnt(0)" ::: "memory");

    bf16x4 ones;
#pragma unroll
    for (int e = 0; e < 4; e++) ones[e] = (bf16)1.0f;

    floatx4 oacc[4][2];                 // [mb=d-block][nb=q-block]
#pragma unroll
    for (int mb = 0; mb < 4; mb++)
#pragma unroll
        for (int nbi = 0; nbi < 2; nbi++) oacc[mb][nbi] = (floatx4){0.f, 0.f, 0.f, 0.f};
    floatx4 lacc[2];                    // ones-MFMA row-sum accumulators
#pragma unroll
    for (int nbi = 0; nbi < 2; nbi++) lacc[nbi] = (floatx4){0.f, 0.f, 0.f, 0.f};

    // DMA one 64-key K+V tile pair (16 KB): 2+2 = 4 vmem/thread
    auto issue = [&](int buf, int k0) {
#pragma unroll
        for (int it = 0; it < 2; it++) {
            int s = it * 256 + tid;          // 0..511 chunk slots
            int row = s >> 3, cl = (s & 7) ^ (row & 7);
            gl2lds16(hK + (size_t)(k0 + row) * 64 + cl * 8, &Ks[buf][s * 8]);
        }
#pragma unroll
        for (int it = 0; it < 2; it++) {
            int s = it * 256 + tid;
            int row = s >> 3, cl = (s & 7) ^ (row & 7);
            gl2lds16(hVt + (size_t)row * SEQ + k0 + cl * 8, &Vt[buf][s * 8]);
        }
    };

    auto compute = [&](int buf) {
#pragma unroll
        for (int kc = 0; kc < 4; kc++) {            // 16-key chunks
            // ---- S'^T: D[key=kc*16+quad*4+r][q=l16] per nb ----
            int krow = kc * 16 + l16;
            bf16x8 kf0 = *(const bf16x8*)&Ks[buf][krow * 64 + ((quad ^ (krow & 7)) * 8)];
            bf16x8 kf1 = *(const bf16x8*)&Ks[buf][krow * 64 + (((4 + quad) ^ (krow & 7)) * 8)];
            bf16x4 p4[2];
#pragma unroll
            for (int nbi = 0; nbi < 2; nbi++) {
                floatx4 s = __builtin_amdgcn_mfma_f32_16x16x32_bf16(
                    kf0, qf[nbi][0], (floatx4){0.f, 0.f, 0.f, 0.f}, 0, 0, 0);
                s = __builtin_amdgcn_mfma_f32_16x16x32_bf16(
                    kf1, qf[nbi][1], s, 0, 0, 0);
#pragma unroll
                for (int r = 0; r < 4; r++)
                    p4[nbi][r] = (bf16)EXP2F(s[r]);
            }
            // ---- PV + row-sum over these 16 keys ----
#pragma unroll
            for (int nbi = 0; nbi < 2; nbi++)
                lacc[nbi] = mfma16(ones, p4[nbi], lacc[nbi]);
#pragma unroll
            for (int mb = 0; mb < 4; mb++) {
                int vrow = mb * 16 + l16;
                int c    = kc * 2 + (quad >> 1);     // 16B chunk holding keys quad*4..+3
                bf16x4 vf = *(const bf16x4*)&Vt[buf][vrow * 64
                                + ((c ^ (vrow & 7)) * 8) + (quad & 1) * 4];
#pragma unroll
                for (int nbi = 0; nbi < 2; nbi++)
                    oacc[mb][nbi] = mfma16(vf, p4[nbi], oacc[mb][nbi]);
            }
        }
    };

    issue(0, 0);
    issue(1, 64);
    for (int t = 0; t < 31; ++t) {
        WAITBAR(4);                      // tile t landed; t+1's 4 still in flight
        if (t < 30) issue((t + 2) % 3, (t + 2) * 64);
        compute(t % 3);
    }
    WAITBAR(0);                          // tile 31: full drain
    compute(1);                          // 31 % 3

    // lacc[nbi][*]: all 4 values = sum over all keys for col q=l16 (A=ones
    // makes D rows identical) -> per-lane reciprocal, no shuffles.
    const int b = bh >> 4, h = bh & 15;
#pragma unroll
    for (int nbi = 0; nbi < 2; nbi++) {
        float rinv = 1.0f / lacc[nbi][0];
        int q = q0 + wq0 + nbi * 16 + l16;
#pragma unroll
        for (int mb = 0; mb < 4; mb++) {
            bf16x4 o4;
#pragma unroll
            for (int r = 0; r < 4; r++) o4[r] = (bf16)(oacc[mb][nbi][r] * rinv);
            *(bf16x4*)&vals[((size_t)b * SEQ + q) * D_MODEL + h * 64 + mb * 16 + quad * 4] = o4;
        }
    }
}

// ---------------------------------------------------------------------------
extern "C" void kernel_launch(void* const* d_in, const int* in_sizes, int n_in,
                              void* d_out, int out_size, void* d_ws, size_t ws_size,
                              hipStream_t stream)
{
    const float* q  = (const float*)d_in[0];
    const float* Wq = (const float*)d_in[1];
    const float* bq = (const float*)d_in[2];
    const float* Wo = (const float*)d_in[3];
    const float* bo = (const float*)d_in[4];
    float* out = (float*)d_out;

    char* ws = (char*)d_ws;
    bf16* qbf    = (bf16*)(ws);                        // 8 MB
    bf16* Wqbf   = (bf16*)(ws + (size_t)( 8 << 20));   // 2 MB
    bf16* Wobf   = (bf16*)(ws + (size_t)(10 << 20));   // 2 MB
    bf16* projbf = (bf16*)(ws + (size_t)(12 << 20));   // 8 MB  [B,H,S,Dh]
    bf16* projT  = (bf16*)(ws + (size_t)(20 << 20));   // 8 MB  [B,H,Dh,S]
    bf16* valsb  = (bf16*)(ws + (size_t)(28 << 20));   // 8 MB  [B,S,D]

    cvt_all<<<6144, 256, 0, stream>>>(q, Wq, Wo, qbf, Wqbf, Wobf);

    // proj = q @ Wq^T + bq -> projbf [B,H,S,Dh] + projT [B,H,Dh,S]
    gemm_bt_bias_t<1><<<512, 256, 0, stream>>>(qbf, Wqbf, bq, (void*)projbf,
                                               projT, M_TOTAL, D_MODEL, D_MODEL);

    flash_attn<<<512, 256, 0, stream>>>(projbf, projT, valsb);

    gemm_bt_bias_t<0><<<512, 256, 0, stream>>>(valsb, Wobf, bo, (void*)out,
                                               nullptr, M_TOTAL, D_MODEL, D_MODEL);
}

// Round 11
// 154.611 us; speedup vs baseline: 1.4874x; 1.0379x over previous
//
#include <hip/hip_runtime.h>

#define D_MODEL 1024
#define N_HEADS 16
#define HEAD_DIM 64
#define SEQ 2048
#define BATCH 2
#define M_TOTAL (BATCH*SEQ)   // 4096

typedef __bf16 bf16;
typedef __bf16 bf16x8 __attribute__((ext_vector_type(8)));
typedef __bf16 bf16x4 __attribute__((ext_vector_type(4)));
typedef float  floatx4 __attribute__((ext_vector_type(4)));
typedef short  shortx4 __attribute__((ext_vector_type(4)));

#if __has_builtin(__builtin_amdgcn_exp2f)
#define EXP2F(x) __builtin_amdgcn_exp2f(x)
#else
#define EXP2F(x) __expf(0.69314718f * (x))
#endif

// 16x16x16 bf16 MFMA: B-operand layout (n=lane&15, k=quad*4+j) exactly matches
// the 16x16x32 D-layout (col=lane&15, row=quad*4+r) -> P feeds PV directly from
// registers, no LDS round trip, no cross-lane movement.
__device__ __forceinline__ floatx4 mfma16(bf16x4 a, bf16x4 b, floatx4 c) {
#if __has_builtin(__builtin_amdgcn_mfma_f32_16x16x16_bf16)
    return __builtin_amdgcn_mfma_f32_16x16x16_bf16(a, b, c, 0, 0, 0);
#else
    return __builtin_amdgcn_mfma_f32_16x16x16bf16_1k(
        __builtin_bit_cast(shortx4, a), __builtin_bit_cast(shortx4, b), c, 0, 0, 0);
#endif
}

// async global->LDS, 16B per lane. LDS dest is wave-uniform base + lane*16;
// conflicts handled by XOR-swizzle of 16B chunks applied to the GLOBAL source
// address (free).
__device__ __forceinline__ void gl2lds16(const bf16* g, bf16* l) {
    __builtin_amdgcn_global_load_lds(
        (const __attribute__((address_space(1))) unsigned int*)g,
        (__attribute__((address_space(3))) unsigned int*)l, 16, 0, 0);
}

// counted-vmcnt barrier: wait until at most N vmem ops outstanding (this
// wave's tile landed), THEN barrier (so after it, ALL waves' loads landed).
#define WAITBAR(N) asm volatile("s_waitcnt vmcnt(" #N ")\n\ts_barrier" ::: "memory")

// ---------------------------------------------------------------------------
// one combined fp32->bf16 conversion for q (1M float4), Wq (256K), Wo (256K)
// ---------------------------------------------------------------------------
__global__ void cvt_all(const float* __restrict__ q, const float* __restrict__ Wq,
                        const float* __restrict__ Wo, bf16* __restrict__ qb,
                        bf16* __restrict__ wqb, bf16* __restrict__ wob) {
    int i = blockIdx.x * 256 + threadIdx.x;       // 0 .. 1572863
    const float* src; bf16* dst; int off;
    if (i < 1048576)      { src = q;  dst = qb;  off = i; }
    else if (i < 1310720) { src = Wq; dst = wqb; off = i - 1048576; }
    else                  { src = Wo; dst = wob; off = i - 1310720; }
    float4 v = ((const float4*)src)[off];
    bf16x4 o;
    o[0] = (bf16)v.x; o[1] = (bf16)v.y; o[2] = (bf16)v.z; o[3] = (bf16)v.w;
    ((bf16x4*)dst)[off] = o;
}

// ---------------------------------------------------------------------------
// GEMM C = A * B^T + bias — r3 version VERBATIM (empirical optimum across 7
// structural variants; staging-DMA-bound at ~73% of the per-CU copy roofline:
// 768KB/CU staged at ~7.4 B/cy/CU. Leave it alone.)
// ---------------------------------------------------------------------------
template<int MODE>
__global__ __launch_bounds__(256, 2)
void gemm_bt_bias_t(const bf16* __restrict__ A, const bf16* __restrict__ B,
                    const float* __restrict__ bias, void* __restrict__ Cout,
                    bf16* __restrict__ Cout2, int M, int N, int K)
{
    // 3 bufs x (As 8192 + Bs 4096 elems) = 36864 elems = 72KB
    __shared__ __align__(16) bf16 smem[36864];

    const int tid  = threadIdx.x;
    const int lane = tid & 63;
    const int wave = tid >> 6;             // 0..3
    const int quad = lane >> 4;
    const int l16  = lane & 15;
    const int lin  = blockIdx.x;           // 0..511
    const int m0   = ((lin & 7) * 4 + ((lin >> 3) & 3)) * 128;  // XCD-pinned m-strip
    const int n0   = (lin >> 5) * 64;
    const int wm   = (wave >> 1) * 64;
    const int wn   = (wave & 1) * 32;

    floatx4 acc[4][2];
#pragma unroll
    for (int i = 0; i < 4; i++)
#pragma unroll
        for (int j = 0; j < 2; j++) acc[i][j] = (floatx4){0.f, 0.f, 0.f, 0.f};

    // stage one 24KB tile pair into buf at elem-offset `base`:
    // A 16KB (4 issues/thread), B 8KB (2 issues) = 6 vmem/thread
    auto issue = [&](int base, int k0) {
#pragma unroll
        for (int it = 0; it < 4; it++) {
            int s = it * 256 + tid;          // 0..1023 chunk slots
            int row = s >> 3, cl = (s & 7) ^ (row & 7);
            gl2lds16(A + (size_t)(m0 + row) * K + k0 + cl * 8, &smem[base + s * 8]);
        }
#pragma unroll
        for (int it = 0; it < 2; it++) {
            int s = it * 256 + tid;          // 0..511
            int row = s >> 3, cl = (s & 7) ^ (row & 7);
            gl2lds16(B + (size_t)(n0 + row) * K + k0 + cl * 8, &smem[base + 8192 + s * 8]);
        }
    };

    auto compute = [&](int base) {
#pragma unroll
        for (int ks = 0; ks < 2; ks++) {
            bf16x8 af[4], bfr[2];
#pragma unroll
            for (int i = 0; i < 4; i++) {
                int row = wm + i * 16 + l16;
                int phys = (ks * 4 + quad) ^ (row & 7);
                af[i] = *(const bf16x8*)&smem[base + row * 64 + phys * 8];
            }
#pragma unroll
            for (int j = 0; j < 2; j++) {
                int row = wn + j * 16 + l16;
                int phys = (ks * 4 + quad) ^ (row & 7);
                bfr[j] = *(const bf16x8*)&smem[base + 8192 + row * 64 + phys * 8];
            }
#pragma unroll
            for (int i = 0; i < 4; i++)
#pragma unroll
                for (int j = 0; j < 2; j++)
                    acc[i][j] = __builtin_amdgcn_mfma_f32_16x16x32_bf16(
                        af[i], bfr[j], acc[i][j], 0, 0, 0);
        }
    };

    const int NT = K >> 6;                  // 16
    issue(0, 0);
    issue(12288, 64);
    for (int t = 0; t < NT - 1; ++t) {
        WAITBAR(6);                         // tile t landed; t+1's 6 still in flight
        if (t + 2 < NT) issue(((t + 2) % 3) * 12288, (t + 2) << 6);
        compute((t % 3) * 12288);
    }
    WAITBAR(0);                             // last tile: full drain
    compute(((NT - 1) % 3) * 12288);

    if constexpr (MODE == 0) {
        float* C = (float*)Cout;
#pragma unroll
        for (int j = 0; j < 2; j++) {
            int col  = n0 + wn + j * 16 + l16;
            float bv = bias[col];
#pragma unroll
            for (int i = 0; i < 4; i++) {
                int rbase = m0 + wm + i * 16 + quad * 4;
#pragma unroll
                for (int r = 0; r < 4; r++)
                    C[(size_t)(rbase + r) * N + col] = acc[i][j][r] + bv;
            }
        }
    } else {
        bf16* Cb = (bf16*)Cout;
        const int h  = n0 >> 6;          // tile spans exactly one head
        const int b  = m0 >> 11;         // tile never crosses batch boundary
        bf16x4 tile[4][2];
#pragma unroll
        for (int j = 0; j < 2; j++) {
            int dL   = wn + j * 16 + l16;            // 0..63
            float bv = bias[n0 + dL];
#pragma unroll
            for (int i = 0; i < 4; i++) {
                int sl = wm + i * 16 + quad * 4;     // local s, 0..127
                int s0 = (m0 & 2047) + sl;
#pragma unroll
                for (int r = 0; r < 4; r++) {
                    float v = acc[i][j][r] + bv;
                    tile[i][j][r] = (bf16)v;
                    Cb[(((size_t)(b * N_HEADS + h) * SEQ + (s0 + r)) << 6) + dL] = (bf16)v;
                }
            }
        }
        // in-LDS transpose: T[dL=64][sL=128] (16KB, reuse smem),
        // 16B-chunk swizzle phys = (sl>>3) ^ (dL&15)
        __syncthreads();
#pragma unroll
        for (int j = 0; j < 2; j++) {
            int dL = wn + j * 16 + l16;
#pragma unroll
            for (int i = 0; i < 4; i++) {
                int sl = wm + i * 16 + quad * 4;
                *(bf16x4*)&smem[dL * 128 + (((sl >> 3) ^ (dL & 15)) * 8) + (sl & 7)] =
                    tile[i][j];
            }
        }
        __syncthreads();
        // coalesced projT stores: thread -> (dL = tid>>2, 4 chunks of 16B)
        {
            int dL    = tid >> 2;
            int sbase = m0 & 2047;
            bf16* dstrow = Cout2 + ((size_t)(b * N_HEADS + h) * 64 + dL) * SEQ + sbase;
#pragma unroll
            for (int cc = 0; cc < 4; cc++) {
                int c    = (tid & 3) * 4 + cc;
                int phys = c ^ (dL & 15);
                *(bf16x8*)(dstrow + c * 8) = *(const bf16x8*)&smem[dL * 128 + phys * 8];
            }
        }
    }
}

// ---------------------------------------------------------------------------
// MFMA flash attention, round 11: KVBLK 64->128, block 256->512 threads
// (8 waves, 32 q/wave unchanged -> 256-q tile), grid 256 = 1 block/CU.
// Rationale: the ONLY variable that ever moved flash duration is per-CU
// barrier/wait instance count (r1: +64/CU -> +6us). This config: 16 tiles x
// 1 block = 16 WAITBAR/CU (was 2 blocks x 32 = 64) with waves/CU PRESERVED
// at 8 (r8's regression was halved waves/CU, not 1 block/CU per se).
// Per-wave compute code identical to the converged kernel; staging = same
// 3-buf/2-deep counted-vmcnt pattern, 4 loads/thread/tile -> WAITBAR(4).
// Vt rows now 128 keys (16 chunks, swizzle c^(row&15), same bank spread).
// LDS 96KB. Q prescale + exp2-direct + ones-MFMA row-sums retained.
// ---------------------------------------------------------------------------
__global__ __launch_bounds__(512, 2)
void flash_attn(const bf16* __restrict__ projbf, const bf16* __restrict__ projT,
                bf16* __restrict__ vals)
{
    __shared__ __align__(16) bf16 Ks[3][128 * 64];   // 3 x 16 KB
    __shared__ __align__(16) bf16 Vt[3][64 * 128];   // 3 x 16 KB -> 96KB total

    const int tid  = threadIdx.x;        // 0..511
    const int lane = tid & 63;
    const int wave = tid >> 6;           // 0..7
    const int quad = lane >> 4;
    const int l16  = lane & 15;
    const int lin  = blockIdx.x;         // 0..255
    const int bh   = (lin & 7) * 4 + (lin >> 6);     // XCD-pinned head (4/XCD)
    const int q0   = ((lin >> 3) & 7) * 256;         // q-tile of 256
    const bf16* hK  = projbf + (size_t)bh * SEQ * 64;
    const bf16* hVt = projT  + (size_t)bh * 64 * SEQ;
    const int wq0  = wave * 32;

    // persistent Q B-frags: qf[nb][ks], n=q (16 per nb), k=d
    // prescaled by 1/(8*ln2) so exp2(S') needs no per-score fma.
    bf16x8 qf[2][2];
#pragma unroll
    for (int nbi = 0; nbi < 2; nbi++)
#pragma unroll
        for (int ks = 0; ks < 2; ks++) {
            bf16x8 v = *(const bf16x8*)(hK + (size_t)(q0 + wq0 + nbi * 16 + l16) * 64
                                        + ks * 32 + quad * 8);
#pragma unroll
            for (int e = 0; e < 8; e++)
                v[e] = (bf16)((float)v[e] * 0.18033688f);
            qf[nbi][ks] = v;
        }
    // drain Q loads so in-loop vmcnt counts only DMA
    asm volatile("s_waitcnt vmcnt(0)" ::: "memory");

    bf16x4 ones;
#pragma unroll
    for (int e = 0; e < 4; e++) ones[e] = (bf16)1.0f;

    floatx4 oacc[4][2];                 // [mb=d-block][nb=q-block]
#pragma unroll
    for (int mb = 0; mb < 4; mb++)
#pragma unroll
        for (int nbi = 0; nbi < 2; nbi++) oacc[mb][nbi] = (floatx4){0.f, 0.f, 0.f, 0.f};
    floatx4 lacc[2];                    // ones-MFMA row-sum accumulators
#pragma unroll
    for (int nbi = 0; nbi < 2; nbi++) lacc[nbi] = (floatx4){0.f, 0.f, 0.f, 0.f};

    // DMA one 128-key K+V tile pair (32 KB): 2+2 = 4 vmem/thread (512 thr)
    auto issue = [&](int buf, int k0) {
#pragma unroll
        for (int it = 0; it < 2; it++) {
            int s = it * 512 + tid;          // 0..1023 (K: 128 rows x 8 chunks)
            int row = s >> 3, cl = (s & 7) ^ (row & 7);
            gl2lds16(hK + (size_t)(k0 + row) * 64 + cl * 8, &Ks[buf][s * 8]);
        }
#pragma unroll
        for (int it = 0; it < 2; it++) {
            int s = it * 512 + tid;          // 0..1023 (Vt: 64 rows x 16 chunks)
            int row = s >> 4, cl = (s & 15) ^ (row & 15);
            gl2lds16(hVt + (size_t)row * SEQ + k0 + cl * 8, &Vt[buf][s * 8]);
        }
    };

    auto compute = [&](int buf) {
#pragma unroll
        for (int kc = 0; kc < 8; kc++) {            // 16-key chunks, 8 per tile
            // ---- S'^T: D[key=kc*16+quad*4+r][q=l16] per nb ----
            int krow = kc * 16 + l16;                // 0..127
            bf16x8 kf0 = *(const bf16x8*)&Ks[buf][krow * 64 + ((quad ^ (krow & 7)) * 8)];
            bf16x8 kf1 = *(const bf16x8*)&Ks[buf][krow * 64 + (((4 + quad) ^ (krow & 7)) * 8)];
            bf16x4 p4[2];
#pragma unroll
            for (int nbi = 0; nbi < 2; nbi++) {
                floatx4 s = __builtin_amdgcn_mfma_f32_16x16x32_bf16(
                    kf0, qf[nbi][0], (floatx4){0.f, 0.f, 0.f, 0.f}, 0, 0, 0);
                s = __builtin_amdgcn_mfma_f32_16x16x32_bf16(
                    kf1, qf[nbi][1], s, 0, 0, 0);
#pragma unroll
                for (int r = 0; r < 4; r++)
                    p4[nbi][r] = (bf16)EXP2F(s[r]);
            }
            // ---- PV + row-sum over these 16 keys ----
#pragma unroll
            for (int nbi = 0; nbi < 2; nbi++)
                lacc[nbi] = mfma16(ones, p4[nbi], lacc[nbi]);
#pragma unroll
            for (int mb = 0; mb < 4; mb++) {
                int vrow = mb * 16 + l16;            // 0..63 (d)
                int c    = kc * 2 + (quad >> 1);     // 16B chunk (keys), 0..15
                bf16x4 vf = *(const bf16x4*)&Vt[buf][vrow * 128
                                + ((c ^ (vrow & 15)) * 8) + (quad & 1) * 4];
#pragma unroll
                for (int nbi = 0; nbi < 2; nbi++)
                    oacc[mb][nbi] = mfma16(vf, p4[nbi], oacc[mb][nbi]);
            }
        }
    };

    // 16 tiles of 128 keys; 3-buf, 2-deep prefetch, counted vmcnt.
    issue(0, 0);
    issue(1, 128);
    for (int t = 0; t < 15; ++t) {
        WAITBAR(4);                      // tile t landed (all waves); t+1 in flight
        if (t < 14) issue((t + 2) % 3, (t + 2) * 128);
        compute(t % 3);
    }
    WAITBAR(0);                          // tile 15: full drain
    compute(0);                          // 15 % 3

    // lacc[nbi][*]: all 4 values = sum over all keys for col q=l16 (A=ones
    // makes D rows identical) -> per-lane reciprocal, no shuffles.
    const int b = bh >> 4, h = bh & 15;
#pragma unroll
    for (int nbi = 0; nbi < 2; nbi++) {
        float rinv = 1.0f / lacc[nbi][0];
        int q = q0 + wq0 + nbi * 16 + l16;
#pragma unroll
        for (int mb = 0; mb < 4; mb++) {
            bf16x4 o4;
#pragma unroll
            for (int r = 0; r < 4; r++) o4[r] = (bf16)(oacc[mb][nbi][r] * rinv);
            *(bf16x4*)&vals[((size_t)b * SEQ + q) * D_MODEL + h * 64 + mb * 16 + quad * 4] = o4;
        }
    }
}

// ---------------------------------------------------------------------------
extern "C" void kernel_launch(void* const* d_in, const int* in_sizes, int n_in,
                              void* d_out, int out_size, void* d_ws, size_t ws_size,
                              hipStream_t stream)
{
    const float* q  = (const float*)d_in[0];
    const float* Wq = (const float*)d_in[1];
    const float* bq = (const float*)d_in[2];
    const float* Wo = (const float*)d_in[3];
    const float* bo = (const float*)d_in[4];
    float* out = (float*)d_out;

    char* ws = (char*)d_ws;
    bf16* qbf    = (bf16*)(ws);                        // 8 MB
    bf16* Wqbf   = (bf16*)(ws + (size_t)( 8 << 20));   // 2 MB
    bf16* Wobf   = (bf16*)(ws + (size_t)(10 << 20));   // 2 MB
    bf16* projbf = (bf16*)(ws + (size_t)(12 << 20));   // 8 MB  [B,H,S,Dh]
    bf16* projT  = (bf16*)(ws + (size_t)(20 << 20));   // 8 MB  [B,H,Dh,S]
    bf16* valsb  = (bf16*)(ws + (size_t)(28 << 20));   // 8 MB  [B,S,D]

    cvt_all<<<6144, 256, 0, stream>>>(q, Wq, Wo, qbf, Wqbf, Wobf);

    // proj = q @ Wq^T + bq -> projbf [B,H,S,Dh] + projT [B,H,Dh,S]
    gemm_bt_bias_t<1><<<512, 256, 0, stream>>>(qbf, Wqbf, bq, (void*)projbf,
                                               projT, M_TOTAL, D_MODEL, D_MODEL);

    flash_attn<<<256, 512, 0, stream>>>(projbf, projT, valsb);

    gemm_bt_bias_t<0><<<512, 256, 0, stream>>>(valsb, Wobf, bo, (void*)out,
                                               nullptr, M_TOTAL, D_MODEL, D_MODEL);
}